// Round 1
// 320.072 us; speedup vs baseline: 1.0071x; 1.0071x over previous
//
#include <hip/hip_runtime.h>
#include <float.h>
#include <limits.h>

// RankLoss round 3: stats_kernel was latency-bound (VALUBusy 37%, HBM 17%,
// occupancy 70%): two serial shuffle-chains per wave with only one row of
// independent work. This round: one wave computes TWO rows (interleaved
// chains hide ds/vmcnt latency), lane-local top-2 tree replaces the eq/cnt
// duplicate machinery (dup max -> m2==m1 falls out of the merge rule), and
// sentinel masking is applied only to the tail chunk (with clamped address:
// both matrices end exactly on a page boundary).

constexpr int B      = 32768;
constexpr int C_ENT  = 1000;   // 250 float4
constexpr int C_REL  = 500;    // 125 float4

// ---------------- round-3 path: per-(row-pair, matrix) wave stats ----------------

// lane-local top-2 (with duplicate handling) over NK float4s.
// merge rule: top1' = max(h1,h2); top2' = max(l1, l2, min(h1,h2))  -> v_max3
template<int NK>
__device__ inline void lane_top2(const float4* v, float& m1, float& m2) {
  float hi[2 * NK], lo[2 * NK];
#pragma unroll
  for (int k = 0; k < NK; ++k) {
    hi[2 * k]     = fmaxf(v[k].x, v[k].y);
    lo[2 * k]     = fminf(v[k].x, v[k].y);
    hi[2 * k + 1] = fmaxf(v[k].z, v[k].w);
    lo[2 * k + 1] = fminf(v[k].z, v[k].w);
  }
#pragma unroll
  for (int half = NK; half >= 1; half >>= 1) {
#pragma unroll
    for (int i = 0; i < half; ++i) {
      const float ha = hi[i], hb = hi[i + half];
      const float la = lo[i], lb = lo[i + half];
      hi[i] = fmaxf(ha, hb);
      lo[i] = fmaxf(fmaxf(la, lb), fminf(ha, hb));  // max3
    }
  }
  m1 = hi[0];
  m2 = lo[0];
}

// lane-local exp-sum (vs global max m1) and min index among elements == m1.
// sentinel elements are -FLT_MAX: exp underflows to 0, eq never fires.
template<int NK>
__device__ inline void lane_z_idx(const float4* v, int lane, float m1, float& z, int& idx) {
  float zp[NK];
  idx = INT_MAX;
#pragma unroll
  for (int k = 0; k < NK; ++k) {
    const int base = 4 * (lane + 64 * k);
    const float a0 = v[k].x, a1 = v[k].y, a2 = v[k].z, a3 = v[k].w;
    zp[k] = (__expf(a0 - m1) + __expf(a1 - m1)) + (__expf(a2 - m1) + __expf(a3 - m1));
    const int i01 = min(a0 == m1 ? base     : INT_MAX, a1 == m1 ? base + 1 : INT_MAX);
    const int i23 = min(a2 == m1 ? base + 2 : INT_MAX, a3 == m1 ? base + 3 : INT_MAX);
    idx = min(idx, min(i01, i23));
  }
  if constexpr (NK == 4) z = (zp[0] + zp[1]) + (zp[2] + zp[3]);
  else                   z = zp[0] + zp[1];
}

// Two rows of the same matrix per wave: independent chains interleave so the
// butterfly ds-latency of one row hides under the VALU work of the other.
template<int NK, int C4>
__device__ inline void wave_stats2(const float* __restrict__ rowA,
                                   const float* __restrict__ rowB,
                                   int lane, int tA, int tB,
                                   float4* __restrict__ outp) {
  const float4* a4 = (const float4*)rowA;
  const float4* b4 = (const float4*)rowB;
  float4 va[NK], vb[NK];
#pragma unroll
  for (int k = 0; k < NK - 1; ++k) {   // full chunks: provably in bounds
    va[k] = a4[lane + 64 * k];
    vb[k] = b4[lane + 64 * k];
  }
  {  // tail chunk: clamp address (rows end on a page boundary), mask whole float4
    const int  i  = lane + 64 * (NK - 1);
    const bool ok = (i < C4);
    const int  ic = ok ? i : (C4 - 1);
    float4 ta = a4[ic], tb = b4[ic];
    ta.x = ok ? ta.x : -FLT_MAX;  ta.y = ok ? ta.y : -FLT_MAX;
    ta.z = ok ? ta.z : -FLT_MAX;  ta.w = ok ? ta.w : -FLT_MAX;
    tb.x = ok ? tb.x : -FLT_MAX;  tb.y = ok ? tb.y : -FLT_MAX;
    tb.z = ok ? tb.z : -FLT_MAX;  tb.w = ok ? tb.w : -FLT_MAX;
    va[NK - 1] = ta;
    vb[NK - 1] = tb;
  }
  const float xa = rowA[tA];   // wave-uniform broadcast loads, issued with the vectors
  const float xb = rowB[tB];

  // ---- lane-local top-2, then joint (m1,m2) butterfly: 12 shuffles per row ----
  float m1a, m2a, m1b, m2b;
  lane_top2<NK>(va, m1a, m2a);
  lane_top2<NK>(vb, m1b, m2b);

#pragma unroll
  for (int off = 32; off; off >>= 1) {
    const float p1a = __shfl_xor(m1a, off), p2a = __shfl_xor(m2a, off);
    const float p1b = __shfl_xor(m1b, off), p2b = __shfl_xor(m2b, off);
    m2a = fmaxf(fmaxf(m2a, p2a), fminf(m1a, p1a));
    m1a = fmaxf(m1a, p1a);
    m2b = fmaxf(fmaxf(m2b, p2b), fminf(m1b, p1b));
    m1b = fmaxf(m1b, p1b);
  }

  // ---- exp pass + argmax (exact ==, fmax/shuffle preserve bits) ----
  float za, zb;
  int   ia, ib;
  lane_z_idx<NK>(va, lane, m1a, za, ia);
  lane_z_idx<NK>(vb, lane, m1b, zb, ib);

#pragma unroll
  for (int off = 32; off; off >>= 1) {
    za += __shfl_xor(za, off);
    zb += __shfl_xor(zb, off);
    ia  = min(ia, __shfl_xor(ia, off));
    ib  = min(ib, __shfl_xor(ib, off));
  }

  if (lane == 0) {
    const float iZa = 1.0f / za;
    const float iZb = 1.0f / zb;
    outp[0] = make_float4(iZa, __expf(m2a - m1a) * iZa, __expf(xa - m1a) * iZa,
                          __int_as_float(ia));
    outp[1] = make_float4(iZb, __expf(m2b - m1b) * iZb, __expf(xb - m1b) * iZb,
                          __int_as_float(ib));
  }
}

__global__ __launch_bounds__(256) void stats2_kernel(
    const float* __restrict__ s, const float* __restrict__ r, const float* __restrict__ o,
    const int* __restrict__ st, const int* __restrict__ rt, const int* __restrict__ ot,
    float4* __restrict__ out4) {
  const int wid  = threadIdx.x >> 6;
  const int lane = threadIdx.x & 63;
  const int gw   = blockIdx.x * 4 + wid;     // grid = 3*B/8 -> gw in [0, 3B/2)
  const int m    = gw >> 14;                 // 16384 row-pairs per matrix
  const int p    = gw & 16383;
  const int row  = 2 * p;
  if (m == 0)
    wave_stats2<4, C_ENT / 4>(s + (size_t)row * C_ENT, s + (size_t)(row + 1) * C_ENT,
                              lane, st[row], st[row + 1], out4 + row);
  else if (m == 1)
    wave_stats2<4, C_ENT / 4>(o + (size_t)row * C_ENT, o + (size_t)(row + 1) * C_ENT,
                              lane, ot[row], ot[row + 1], out4 + B + row);
  else
    wave_stats2<2, C_REL / 4>(r + (size_t)row * C_REL, r + (size_t)(row + 1) * C_REL,
                              lane, rt[row], rt[row + 1], out4 + 2 * B + row);
}

__global__ __launch_bounds__(256) void combine_kernel(
    const float4* __restrict__ stat4,
    const int* __restrict__ st, const int* __restrict__ rt, const int* __restrict__ ot,
    float* __restrict__ partial) {
  const int row = blockIdx.x * 256 + threadIdx.x;   // grid = B/256
  const float4 S = stat4[row];           // m=0
  const float4 O = stat4[B + row];       // m=1
  const float4 R = stat4[2 * B + row];   // m=2
  const float gt   = S.z * R.z * O.z;
  const float top1 = S.x * R.x * O.x;
  // second-smallest of the 8 top2-products = min of the three one-swap products
  const float c1 = S.x * R.y * O.y;
  const float c2 = S.y * R.x * O.y;
  const float c3 = S.y * R.y * O.x;
  const float second = fminf(c1, fminf(c2, c3));
  const bool cond = (__float_as_int(S.w) == st[row]) &&
                    (__float_as_int(R.w) == rt[row]) &&
                    (__float_as_int(O.w) == ot[row]);
  const float pre = cond ? second : top1;
  partial[row] = fmaxf(1.0f - gt + pre, 0.0f);
}

// ---------------- round-1 fallback: one wave per row ----------------

__device__ inline void combine_stats(float& m1, int& i1, float& m2, float& Z,
                                     float bm1, int bi1, float bm2, float bZ) {
  bool bwin = (bm1 > m1) || (bm1 == m1 && bi1 < i1);
  float wm1 = bwin ? bm1 : m1;
  int   wi1 = bwin ? bi1 : i1;
  float wm2 = bwin ? bm2 : m2;
  float lm1 = bwin ? m1  : bm1;
  float wZ  = bwin ? bZ  : Z;
  float lZ  = bwin ? Z   : bZ;
  m1 = wm1; i1 = wi1;
  m2 = fmaxf(wm2, lm1);
  Z  = wZ + lZ * __expf(lm1 - wm1);
}

template<int NK, int C4>
__device__ inline void row_stats(const float* __restrict__ row, int lane, int target,
                                 float& p_top1, float& p_top2, int& amax, float& p_tgt) {
  const float4* row4 = (const float4*)row;
  float4 v[NK];
#pragma unroll
  for (int k = 0; k < NK; ++k) {
    int idx = lane + 64 * k;
    v[k] = (idx < C4) ? row4[idx] : make_float4(-FLT_MAX, -FLT_MAX, -FLT_MAX, -FLT_MAX);
  }
  float m1 = -FLT_MAX, m2 = -FLT_MAX;
  int   i1 = 0x7fffffff;
#pragma unroll
  for (int k = 0; k < NK; ++k) {
    int base = 4 * (lane + 64 * k);
    float a0 = v[k].x, a1 = v[k].y, a2 = v[k].z, a3 = v[k].w;
    if (a0 > m1) { m2 = m1; m1 = a0; i1 = base;     } else if (a0 > m2) m2 = a0;
    if (a1 > m1) { m2 = m1; m1 = a1; i1 = base + 1; } else if (a1 > m2) m2 = a1;
    if (a2 > m1) { m2 = m1; m1 = a2; i1 = base + 2; } else if (a2 > m2) m2 = a2;
    if (a3 > m1) { m2 = m1; m1 = a3; i1 = base + 3; } else if (a3 > m2) m2 = a3;
  }
  float Z = 0.f;
#pragma unroll
  for (int k = 0; k < NK; ++k) {
    Z += __expf(v[k].x - m1); Z += __expf(v[k].y - m1);
    Z += __expf(v[k].z - m1); Z += __expf(v[k].w - m1);
  }
#pragma unroll
  for (int off = 32; off > 0; off >>= 1) {
    float bm1 = __shfl_xor(m1, off);
    int   bi1 = __shfl_xor(i1, off);
    float bm2 = __shfl_xor(m2, off);
    float bZ  = __shfl_xor(Z,  off);
    combine_stats(m1, i1, m2, Z, bm1, bi1, bm2, bZ);
  }
  float invZ = 1.0f / Z;
  float xt   = row[target];
  p_top1 = invZ;
  p_top2 = __expf(m2 - m1) * invZ;
  p_tgt  = __expf(xt - m1) * invZ;
  amax   = i1;
}

template<bool ATOMIC>
__global__ __launch_bounds__(256) void rank_loss_kernel(
    const float* __restrict__ s, const float* __restrict__ r, const float* __restrict__ o,
    const int* __restrict__ st, const int* __restrict__ rt, const int* __restrict__ ot,
    float* __restrict__ partial, float* __restrict__ out) {
  const int wid  = threadIdx.x >> 6;
  const int lane = threadIdx.x & 63;
  const int row  = blockIdx.x * 4 + wid;

  const float* srow = s + (size_t)row * C_ENT;
  const float* rrow = r + (size_t)row * C_REL;
  const float* orow = o + (size_t)row * C_ENT;
  const int tS = st[row], tR = rt[row], tO = ot[row];

  float sp0, sp1, spt; int sa;
  float rp0, rp1, rpt; int ra;
  float op0, op1, opt; int oa;
  row_stats<4, C_ENT / 4>(srow, lane, tS, sp0, sp1, sa, spt);
  row_stats<2, C_REL / 4>(rrow, lane, tR, rp0, rp1, ra, rpt);
  row_stats<4, C_ENT / 4>(orow, lane, tO, op0, op1, oa, opt);

  if (lane == 0) {
    float gt   = spt * rpt * opt;
    float top1 = sp0 * rp0 * op0;
    float c1 = sp0 * rp1 * op1;
    float c2 = sp1 * rp0 * op1;
    float c3 = sp1 * rp1 * op0;
    float second = fminf(c1, fminf(c2, c3));
    bool cond = (sa == tS) && (ra == tR) && (oa == tO);
    float pre = cond ? second : top1;
    float val = fmaxf(1.0f - gt + pre, 0.0f);
    if (ATOMIC) atomicAdd(out, val * (1.0f / (float)B));
    else        partial[row] = val;
  }
}

// ---------------- final mean reduction ----------------

__global__ __launch_bounds__(1024) void reduce_sum_kernel(const float* __restrict__ p,
                                                          float* __restrict__ out) {
  const float4* p4 = (const float4*)p;
  float sum = 0.f;
  for (int i = threadIdx.x; i < B / 4; i += 1024) {
    float4 v = p4[i];
    sum += (v.x + v.y) + (v.z + v.w);
  }
#pragma unroll
  for (int off = 32; off > 0; off >>= 1) sum += __shfl_xor(sum, off);
  __shared__ float lds[16];
  if ((threadIdx.x & 63) == 0) lds[threadIdx.x >> 6] = sum;
  __syncthreads();
  if (threadIdx.x == 0) {
    float t = 0.f;
#pragma unroll
    for (int i = 0; i < 16; ++i) t += lds[i];
    out[0] = t * (1.0f / (float)B);
  }
}

extern "C" void kernel_launch(void* const* d_in, const int* in_sizes, int n_in,
                              void* d_out, int out_size, void* d_ws, size_t ws_size,
                              hipStream_t stream) {
  const float* s  = (const float*)d_in[0];
  const float* r  = (const float*)d_in[1];
  const float* o  = (const float*)d_in[2];
  const int*   st = (const int*)d_in[3];
  const int*   rt = (const int*)d_in[4];
  const int*   ot = (const int*)d_in[5];
  float* out = (float*)d_out;

  const size_t statBytes = (size_t)3 * B * sizeof(float4);          // 1.5 MiB
  if (ws_size >= statBytes + (size_t)B * sizeof(float)) {
    float4* stat4  = (float4*)d_ws;
    float* partial = (float*)((char*)d_ws + statBytes);
    stats2_kernel<<<3 * B / 8, 256, 0, stream>>>(s, r, o, st, rt, ot, stat4);
    combine_kernel<<<B / 256, 256, 0, stream>>>(stat4, st, rt, ot, partial);
    reduce_sum_kernel<<<1, 1024, 0, stream>>>(partial, out);
  } else if (ws_size >= (size_t)B * sizeof(float)) {
    float* partial = (float*)d_ws;
    rank_loss_kernel<false><<<B / 4, 256, 0, stream>>>(s, r, o, st, rt, ot, partial, nullptr);
    reduce_sum_kernel<<<1, 1024, 0, stream>>>(partial, out);
  } else {
    hipMemsetAsync(d_out, 0, sizeof(float), stream);
    rank_loss_kernel<true><<<B / 4, 256, 0, stream>>>(s, r, o, st, rt, ot, nullptr, out);
  }
}